// Round 1
// baseline (1013.748 us; speedup 1.0000x reference)
//
#include <hip/hip_runtime.h>
#include <cstdint>

// ---------------------------------------------------------------------------
// Types & helpers
// ---------------------------------------------------------------------------
typedef __attribute__((ext_vector_type(8))) short  bf16x8;   // 8 bf16 = 4 VGPR
typedef __attribute__((ext_vector_type(4))) float  f32x4;
typedef __attribute__((ext_vector_type(4))) unsigned int uint4v;
typedef __attribute__((ext_vector_type(2))) unsigned int uint2v;

__device__ __forceinline__ float bf2f(unsigned short b) {
    union { unsigned int u; float f; } v; v.u = ((unsigned int)b) << 16; return v.f;
}
__device__ __forceinline__ unsigned short f2bf(float f) {
    union { float f; unsigned int u; } v; v.f = f;
    unsigned int r = v.u + 0x7FFFu + ((v.u >> 16) & 1u);   // RNE
    return (unsigned short)(r >> 16);
}

// ---------------------------------------------------------------------------
// RMSNorm: fp32 [T,4096] -> bf16 [T,4096]
// ---------------------------------------------------------------------------
__global__ __launch_bounds__(256)
void rmsnorm_kernel(const float* __restrict__ x, const float* __restrict__ wgt,
                    unsigned short* __restrict__ out)
{
    const int t = blockIdx.x, tid = threadIdx.x;
    const float4* xr = (const float4*)(x + (size_t)t * 4096);
    float4 v[4];
    float ss = 0.f;
#pragma unroll
    for (int j = 0; j < 4; j++) {
        v[j] = xr[(j << 8) + tid];
        ss += v[j].x*v[j].x + v[j].y*v[j].y + v[j].z*v[j].z + v[j].w*v[j].w;
    }
#pragma unroll
    for (int m = 1; m < 64; m <<= 1) ss += __shfl_xor(ss, m);
    __shared__ float red[4];
    if ((tid & 63) == 0) red[tid >> 6] = ss;
    __syncthreads();
    float tot = red[0] + red[1] + red[2] + red[3];
    float rs = rsqrtf(tot * (1.f / 4096.f) + 1e-6f);
    const float4* wr = (const float4*)wgt;
#pragma unroll
    for (int j = 0; j < 4; j++) {
        float4 wv = wr[(j << 8) + tid];
        float4 xv = v[j];
        unsigned int p0 = (unsigned int)f2bf(xv.x*rs*wv.x) | ((unsigned int)f2bf(xv.y*rs*wv.y) << 16);
        unsigned int p1 = (unsigned int)f2bf(xv.z*rs*wv.z) | ((unsigned int)f2bf(xv.w*rs*wv.w) << 16);
        uint2v pk = {p0, p1};
        *(uint2v*)(&out[(size_t)t*4096 + (size_t)(((j << 8) + tid) << 2)]) = pk;
    }
}

// ---------------------------------------------------------------------------
// AWQ GEMM: C[1024,N] = A[1024,K](bf16) @ dequant(qw,qz,sc)[K,N]
// EPI 0: write bf16. EPI 1: write fp32 = acc + res(fp32).
// Tile 128x128, BK=64, 256 threads (2x2 waves, each 64x64).
// LDS XOR-swizzle: 16B slot s of row r stored at s^(r&7).
// ---------------------------------------------------------------------------
template<int EPI>
__global__ __launch_bounds__(256, 3)
void awq_gemm(const unsigned short* __restrict__ A,
              const int* __restrict__ qw, const int* __restrict__ qz,
              const float* __restrict__ sc,
              void* __restrict__ outp, const float* __restrict__ res,
              int N, int K)
{
    __shared__ unsigned short As[128 * 64];
    __shared__ unsigned short Bs[128 * 64];   // Bt[n][k]
    const int tid  = threadIdx.x;
    const int lane = tid & 63;
    const int wid  = tid >> 6;
    const int wm   = wid >> 1, wn = wid & 1;
    const int m0   = blockIdx.y << 7;
    const int n0   = blockIdx.x << 7;
    const int NW   = N >> 3;

    const int nl   = tid & 127;        // local output col for dequant duty
    const int gn   = n0 + nl;
    const int gwc  = gn >> 3;          // packed-word column
    const int nsh  = (gn & 7) << 2;    // nibble shift
    const int kgb  = tid >> 7;         // 0/1 -> kg parity

    f32x4 acc[4][4];
#pragma unroll
    for (int i = 0; i < 4; i++)
#pragma unroll
        for (int j = 0; j < 4; j++) { f32x4 z = {0.f,0.f,0.f,0.f}; acc[i][j] = z; }

    for (int k0 = 0; k0 < K; k0 += 64) {
        const int g = k0 >> 7;   // AWQ group (G=128)
        const float scale = sc[(size_t)g * N + gn];
        const int   zw    = qz[(size_t)g * NW + gwc];
        const float nzs   = -(float)((zw >> nsh) & 0xF) * scale;

        __syncthreads();   // previous MFMA reads done

        // ---- stage A: 1024 slots of 16B (swizzled content via source offset)
#pragma unroll
        for (int j = 0; j < 4; j++) {
            int slot = (j << 8) + tid;
            int row = slot >> 3, s = slot & 7;
            const uint4v* src = (const uint4v*)(A + (size_t)(m0 + row) * K + k0 + ((s ^ (row & 7)) << 3));
            *(uint4v*)(&As[(row << 6) + (s << 3)]) = *src;
        }
        // ---- stage B: dequant 8 k-rows per task, write k-contiguous 16B
#pragma unroll
        for (int i = 0; i < 4; i++) {
            int kg = kgb + (i << 1);
            const int* wp = qw + (size_t)(k0 + (kg << 3)) * NW + gwc;
            unsigned int pk[4];
#pragma unroll
            for (int jj = 0; jj < 4; jj++) {
                int w0 = wp[(size_t)(2 * jj) * NW];
                int w1 = wp[(size_t)(2 * jj + 1) * NW];
                float f0 = (float)((w0 >> nsh) & 0xF) * scale + nzs;
                float f1 = (float)((w1 >> nsh) & 0xF) * scale + nzs;
                pk[jj] = (unsigned int)f2bf(f0) | ((unsigned int)f2bf(f1) << 16);
            }
            int s = kg ^ (nl & 7);
            uint4v bv = {pk[0], pk[1], pk[2], pk[3]};
            *(uint4v*)(&Bs[(nl << 6) + (s << 3)]) = bv;
        }
        __syncthreads();   // tiles ready

        // ---- MFMA
#pragma unroll
        for (int kk = 0; kk < 2; kk++) {
            bf16x8 af[4], bfv[4];
#pragma unroll
            for (int mi = 0; mi < 4; mi++) {
                int r = (wm << 6) + (mi << 4) + (lane & 15);
                int s = (kk << 2) + (lane >> 4);
                af[mi] = *(const bf16x8*)(&As[(r << 6) + ((s ^ (r & 7)) << 3)]);
            }
#pragma unroll
            for (int ni = 0; ni < 4; ni++) {
                int r = (wn << 6) + (ni << 4) + (lane & 15);
                int s = (kk << 2) + (lane >> 4);
                bfv[ni] = *(const bf16x8*)(&Bs[(r << 6) + ((s ^ (r & 7)) << 3)]);
            }
#pragma unroll
            for (int mi = 0; mi < 4; mi++)
#pragma unroll
                for (int ni = 0; ni < 4; ni++)
                    acc[mi][ni] = __builtin_amdgcn_mfma_f32_16x16x32_bf16(af[mi], bfv[ni], acc[mi][ni], 0, 0, 0);
        }
    }

    // ---- epilogue: C/D layout col=lane&15, row=(lane>>4)*4+reg
    const int rbase = m0 + (wm << 6) + ((lane >> 4) << 2);
    const int cbase = n0 + (wn << 6) + (lane & 15);
#pragma unroll
    for (int mi = 0; mi < 4; mi++) {
#pragma unroll
        for (int r = 0; r < 4; r++) {
            int row = rbase + (mi << 4) + r;
#pragma unroll
            for (int ni = 0; ni < 4; ni++) {
                int col = cbase + (ni << 4);
                float v = acc[mi][ni][r];
                if (EPI == 0) {
                    ((unsigned short*)outp)[(size_t)row * N + col] = f2bf(v);
                } else {
                    ((float*)outp)[(size_t)row * N + col] = v + res[(size_t)row * N + col];
                }
            }
        }
    }
}

// ---------------------------------------------------------------------------
// RoPE + layout glue: qkv bf16 [T,12288] ->
//   Qr [32][1024][128] (pre-scaled by 1/sqrt(128)), Kr [32][1024][128],
//   Vt [32][128][1024] (transposed V)
// ---------------------------------------------------------------------------
__global__ __launch_bounds__(256)
void rope_kernel(const int* __restrict__ positions, const unsigned short* __restrict__ qkv,
                 unsigned short* __restrict__ Qr, unsigned short* __restrict__ Kr,
                 unsigned short* __restrict__ Vtp)
{
    const int t = blockIdx.x, tid = threadIdx.x;
    const float p = (float)positions[t];
    const unsigned short* row = qkv + (size_t)t * 12288;
#pragma unroll 4
    for (int it = 0; it < 16; it++) {
        int task = (it << 8) + tid;           // 0..4095: [isK][head][i]
        int i   = task & 63;
        int hh  = (task >> 6) & 31;
        int isK = task >> 11;
        // inv_freq = 10000^{-i/64} = exp(-i * ln(10000)/64)
        float fr = p * __expf(-(float)i * 0.14391156831f);
        float s, c;
        __sincosf(fr, &s, &c);
        const unsigned short* src = row + (isK << 12) + (hh << 7);
        float x1 = bf2f(src[i]);
        float x2 = bf2f(src[64 + i]);
        float o1 = x1 * c - x2 * s;
        float o2 = x2 * c + x1 * s;
        if (!isK) { o1 *= 0.08838834764831845f; o2 *= 0.08838834764831845f; }
        unsigned short* dst = (isK ? Kr : Qr) + ((size_t)hh * 1024 + t) * 128;
        dst[i]      = f2bf(o1);
        dst[64 + i] = f2bf(o2);
    }
#pragma unroll 4
    for (int it = 0; it < 16; it++) {
        int task = (it << 8) + tid;           // 0..4095: [head][d]
        int d = task & 127, hh = task >> 7;
        Vtp[((size_t)hh * 128 + d) * 1024 + t] = row[8192 + task];
    }
}

// ---------------------------------------------------------------------------
// Flash attention (causal). Block = (qt, head). 4 waves x 16 q-rows.
// K tiles of 64 rows staged in LDS (swizzled); V from transposed Vt.
// ---------------------------------------------------------------------------
__global__ __launch_bounds__(256, 2)
void attn_kernel(const unsigned short* __restrict__ Qr, const unsigned short* __restrict__ Kr,
                 const unsigned short* __restrict__ Vtp, unsigned short* __restrict__ attn_out)
{
    __shared__ unsigned short Ks[64 * 128];    // [krow][d]
    __shared__ unsigned short Vs[128 * 64];    // [d][krow]
    __shared__ unsigned short Ps[4][16 * 64];  // per-wave P
    const int tid = threadIdx.x, lane = tid & 63, w = tid >> 6;
    const int qt = blockIdx.x, h = blockIdx.y;

    const unsigned short* Qh = Qr + ((size_t)h * 1024 + (size_t)qt * 64) * 128;

    bf16x8 qf[4];
#pragma unroll
    for (int kk = 0; kk < 4; kk++)
        qf[kk] = *(const bf16x8*)(Qh + (size_t)((w << 4) + (lane & 15)) * 128 + (kk << 5) + ((lane >> 4) << 3));

    f32x4 o[8];
#pragma unroll
    for (int i = 0; i < 8; i++) { f32x4 z = {0.f,0.f,0.f,0.f}; o[i] = z; }
    float Mr[4] = {-1e30f, -1e30f, -1e30f, -1e30f};
    float Lr[4] = {0.f, 0.f, 0.f, 0.f};
    const int qrow0 = (qt << 6) + (w << 4) + ((lane >> 4) << 2);

    for (int kt = 0; kt <= qt; kt++) {
        __syncthreads();
        // stage K tile: 64 rows x 16 slots (16B); swizzle low 3 slot bits
#pragma unroll
        for (int j = 0; j < 4; j++) {
            int slot = (j << 8) + tid;
            int rw = slot >> 4, s = slot & 15;
            int ssrc = (s & 8) | ((s ^ (rw & 7)) & 7);
            const uint4v* src = (const uint4v*)(Kr + ((size_t)h * 1024 + (size_t)kt * 64 + rw) * 128 + (ssrc << 3));
            *(uint4v*)(&Ks[(rw << 7) + (s << 3)]) = *src;
        }
        // stage V tile: 128 d-rows x 8 slots
#pragma unroll
        for (int j = 0; j < 4; j++) {
            int slot = (j << 8) + tid;
            int rw = slot >> 3, s = slot & 7;
            const uint4v* src = (const uint4v*)(Vtp + ((size_t)h * 128 + rw) * 1024 + (kt << 6) + ((s ^ (rw & 7)) << 3));
            *(uint4v*)(&Vs[(rw << 6) + (s << 3)]) = *src;
        }
        __syncthreads();

        // S = Q K^T  (A=Q frags, B=K rows as K-major fragments)
        f32x4 sc4[4];
#pragma unroll
        for (int ni = 0; ni < 4; ni++) { f32x4 z = {0.f,0.f,0.f,0.f}; sc4[ni] = z; }
#pragma unroll
        for (int kk = 0; kk < 4; kk++) {
#pragma unroll
            for (int ni = 0; ni < 4; ni++) {
                int r = (ni << 4) + (lane & 15);
                int s = (kk << 2) + (lane >> 4);
                int sp = (s & 8) | ((s ^ (r & 7)) & 7);
                bf16x8 kf = *(const bf16x8*)(&Ks[(r << 7) + (sp << 3)]);
                sc4[ni] = __builtin_amdgcn_mfma_f32_16x16x32_bf16(qf[kk], kf, sc4[ni], 0, 0, 0);
            }
        }

        // online softmax
#pragma unroll
        for (int r = 0; r < 4; r++) {
            int qg = qrow0 + r;
            float mx = -1e30f;
#pragma unroll
            for (int ni = 0; ni < 4; ni++) {
                int kg_ = (kt << 6) + (ni << 4) + (lane & 15);
                float v = sc4[ni][r];
                if (kt == qt && kg_ > qg) { v = -1e30f; sc4[ni][r] = v; }
                mx = fmaxf(mx, v);
            }
#pragma unroll
            for (int m_ = 1; m_ < 16; m_ <<= 1) mx = fmaxf(mx, __shfl_xor(mx, m_));
            float mnew  = fmaxf(Mr[r], mx);
            float alpha = __expf(Mr[r] - mnew);
            Mr[r] = mnew;
            float rs = 0.f;
#pragma unroll
            for (int ni = 0; ni < 4; ni++) {
                float pv = __expf(sc4[ni][r] - mnew);
                sc4[ni][r] = pv;
                rs += pv;
            }
#pragma unroll
            for (int m_ = 1; m_ < 16; m_ <<= 1) rs += __shfl_xor(rs, m_);
            Lr[r] = Lr[r] * alpha + rs;
#pragma unroll
            for (int nd = 0; nd < 8; nd++) o[nd][r] *= alpha;
        }

        // P -> LDS (per-wave, swizzled), then PV
#pragma unroll
        for (int r = 0; r < 4; r++) {
            int qr = ((lane >> 4) << 2) + r;
#pragma unroll
            for (int ni = 0; ni < 4; ni++) {
                int col = (ni << 4) + (lane & 15);
                int phys = (col >> 3) ^ (qr & 7);
                Ps[w][(qr << 6) + (phys << 3) + (col & 7)] = f2bf(sc4[ni][r]);
            }
        }
#pragma unroll
        for (int kk2 = 0; kk2 < 2; kk2++) {
            int rowp = lane & 15;
            int sl = (kk2 << 2) + (lane >> 4);
            bf16x8 pa = *(const bf16x8*)(&Ps[w][(rowp << 6) + ((sl ^ (rowp & 7)) << 3)]);
#pragma unroll
            for (int nd = 0; nd < 8; nd++) {
                int rv = (nd << 4) + (lane & 15);
                bf16x8 vb = *(const bf16x8*)(&Vs[(rv << 6) + ((sl ^ (rv & 7)) << 3)]);
                o[nd] = __builtin_amdgcn_mfma_f32_16x16x32_bf16(pa, vb, o[nd], 0, 0, 0);
            }
        }
    }

    // finalize: divide by row sums, write bf16 [T, 4096]
#pragma unroll
    for (int r = 0; r < 4; r++) {
        float inv = 1.0f / Lr[r];
        int trow = qrow0 + r;
#pragma unroll
        for (int nd = 0; nd < 8; nd++) {
            int col = (h << 7) + (nd << 4) + (lane & 15);
            attn_out[(size_t)trow * 4096 + col] = f2bf(o[nd][r] * inv);
        }
    }
}

// ---------------------------------------------------------------------------
// silu(gate) * up, bf16, in-place into `up` (recomputed each call)
// ---------------------------------------------------------------------------
__global__ __launch_bounds__(256)
void silu_mul_kernel(const unsigned short* __restrict__ gate, unsigned short* __restrict__ up)
{
    size_t idx = ((size_t)blockIdx.x * 256 + threadIdx.x) * 8;
    uint4v g = *(const uint4v*)(gate + idx);
    uint4v u = *(const uint4v*)(up + idx);
    unsigned int outp[4];
#pragma unroll
    for (int j = 0; j < 4; j++) {
        unsigned int gw = g[j], uw = u[j];
        float g0 = bf2f((unsigned short)(gw & 0xFFFF)), g1 = bf2f((unsigned short)(gw >> 16));
        float u0 = bf2f((unsigned short)(uw & 0xFFFF)), u1 = bf2f((unsigned short)(uw >> 16));
        float s0 = g0 / (1.f + __expf(-g0)) * u0;
        float s1 = g1 / (1.f + __expf(-g1)) * u1;
        outp[j] = (unsigned int)f2bf(s0) | ((unsigned int)f2bf(s1) << 16);
    }
    uint4v ov = {outp[0], outp[1], outp[2], outp[3]};
    *(uint4v*)(up + idx) = ov;
}

// ---------------------------------------------------------------------------
// Launcher
// ---------------------------------------------------------------------------
extern "C" void kernel_launch(void* const* d_in, const int* in_sizes, int n_in,
                              void* d_out, int out_size, void* d_ws, size_t ws_size,
                              hipStream_t stream)
{
    const int*   positions = (const int*)  d_in[0];
    const float* hidden    = (const float*)d_in[1];
    const float* ln1       = (const float*)d_in[2];
    const float* ln2       = (const float*)d_in[3];
    const int*   qkv_qw    = (const int*)  d_in[4];
    const int*   qkv_qz    = (const int*)  d_in[5];
    const float* qkv_sc    = (const float*)d_in[6];
    const int*   o_qw      = (const int*)  d_in[7];
    const int*   o_qz      = (const int*)  d_in[8];
    const float* o_sc      = (const float*)d_in[9];
    const int*   gate_qw   = (const int*)  d_in[10];
    const int*   gate_qz   = (const int*)  d_in[11];
    const float* gate_sc   = (const float*)d_in[12];
    const int*   up_qw     = (const int*)  d_in[13];
    const int*   up_qz     = (const int*)  d_in[14];
    const float* up_sc     = (const float*)d_in[15];
    const int*   down_qw   = (const int*)  d_in[16];
    const int*   down_qz   = (const int*)  d_in[17];
    const float* down_sc   = (const float*)d_in[18];

    char* ws = (char*)d_ws;
    // workspace layout (bytes); regions reused across phases
    unsigned short* xln   = (unsigned short*)(ws + 0);          //  8.39 MB [T,H] bf16
    unsigned short* qkvb  = (unsigned short*)(ws + 8388608);    // 25.17 MB [T,3H] bf16
    unsigned short* Qrp   = (unsigned short*)(ws + 33554432);   //  8.39 MB
    unsigned short* Krp   = (unsigned short*)(ws + 41943040);   //  8.39 MB
    unsigned short* Vtp   = (unsigned short*)(ws + 50331648);   //  8.39 MB
    unsigned short* attnb = (unsigned short*)(ws + 58720256);   //  8.39 MB [T,H] bf16
    float*          hid   = (float*)        (ws + 67108864);    // 16.78 MB [T,H] f32
    unsigned short* x2    = (unsigned short*)(ws + 0);          // reuse xln
    unsigned short* gateb = (unsigned short*)(ws + 8388608);    // reuse qkvb (22.54 MB)
    unsigned short* upb   = (unsigned short*)(ws + 33554432);   // reuse Q/K (22.54 MB)

    // --- attention block ---
    rmsnorm_kernel<<<1024, 256, 0, stream>>>(hidden, ln1, xln);
    awq_gemm<0><<<dim3(96, 8), 256, 0, stream>>>(xln, qkv_qw, qkv_qz, qkv_sc,
                                                 (void*)qkvb, nullptr, 12288, 4096);
    rope_kernel<<<1024, 256, 0, stream>>>(positions, qkvb, Qrp, Krp, Vtp);
    attn_kernel<<<dim3(16, 32), 256, 0, stream>>>(Qrp, Krp, Vtp, attnb);
    awq_gemm<1><<<dim3(32, 8), 256, 0, stream>>>(attnb, o_qw, o_qz, o_sc,
                                                 (void*)hid, hidden, 4096, 4096);
    // --- MLP block ---
    rmsnorm_kernel<<<1024, 256, 0, stream>>>(hid, ln2, x2);
    awq_gemm<0><<<dim3(86, 8), 256, 0, stream>>>(x2, gate_qw, gate_qz, gate_sc,
                                                 (void*)gateb, nullptr, 11008, 4096);
    awq_gemm<0><<<dim3(86, 8), 256, 0, stream>>>(x2, up_qw, up_qz, up_sc,
                                                 (void*)upb, nullptr, 11008, 4096);
    silu_mul_kernel<<<5504, 256, 0, stream>>>(gateb, upb);   // 1024*11008/8/256
    awq_gemm<1><<<dim3(32, 8), 256, 0, stream>>>(upb, down_qw, down_qz, down_sc,
                                                 d_out, hid, 4096, 11008);
}

// Round 2
// 776.769 us; speedup vs baseline: 1.3051x; 1.3051x over previous
//
#include <hip/hip_runtime.h>
#include <cstdint>

// ---------------------------------------------------------------------------
// Types & helpers
// ---------------------------------------------------------------------------
typedef __attribute__((ext_vector_type(8))) short  bf16x8;   // 8 bf16 = 4 VGPR
typedef __attribute__((ext_vector_type(4))) float  f32x4;
typedef __attribute__((ext_vector_type(4))) unsigned int uint4v;
typedef __attribute__((ext_vector_type(2))) unsigned int uint2v;

__device__ __forceinline__ float bf2f(unsigned short b) {
    union { unsigned int u; float f; } v; v.u = ((unsigned int)b) << 16; return v.f;
}
__device__ __forceinline__ unsigned short f2bf(float f) {
    union { float f; unsigned int u; } v; v.f = f;
    unsigned int r = v.u + 0x7FFFu + ((v.u >> 16) & 1u);   // RNE
    return (unsigned short)(r >> 16);
}

// ---------------------------------------------------------------------------
// RMSNorm: fp32 [T,4096] -> bf16 [T,4096]
// ---------------------------------------------------------------------------
__global__ __launch_bounds__(256)
void rmsnorm_kernel(const float* __restrict__ x, const float* __restrict__ wgt,
                    unsigned short* __restrict__ out)
{
    const int t = blockIdx.x, tid = threadIdx.x;
    const float4* xr = (const float4*)(x + (size_t)t * 4096);
    float4 v[4];
    float ss = 0.f;
#pragma unroll
    for (int j = 0; j < 4; j++) {
        v[j] = xr[(j << 8) + tid];
        ss += v[j].x*v[j].x + v[j].y*v[j].y + v[j].z*v[j].z + v[j].w*v[j].w;
    }
#pragma unroll
    for (int m = 1; m < 64; m <<= 1) ss += __shfl_xor(ss, m);
    __shared__ float red[4];
    if ((tid & 63) == 0) red[tid >> 6] = ss;
    __syncthreads();
    float tot = red[0] + red[1] + red[2] + red[3];
    float rs = rsqrtf(tot * (1.f / 4096.f) + 1e-6f);
    const float4* wr = (const float4*)wgt;
#pragma unroll
    for (int j = 0; j < 4; j++) {
        float4 wv = wr[(j << 8) + tid];
        float4 xv = v[j];
        unsigned int p0 = (unsigned int)f2bf(xv.x*rs*wv.x) | ((unsigned int)f2bf(xv.y*rs*wv.y) << 16);
        unsigned int p1 = (unsigned int)f2bf(xv.z*rs*wv.z) | ((unsigned int)f2bf(xv.w*rs*wv.w) << 16);
        uint2v pk = {p0, p1};
        *(uint2v*)(&out[(size_t)t*4096 + (size_t)(((j << 8) + tid) << 2)]) = pk;
    }
}

// ---------------------------------------------------------------------------
// AWQ GEMM: C[1024,N] = A[1024,K](bf16) @ dequant(qw,qz,sc)[K,N]
// EPI 0: write bf16. EPI 1: write fp32 = acc + res(fp32).
// Tile 256x64, BK=64, 512 threads (8 waves, 4M x 2N, each wave 64x32).
// Double-buffered swizzled LDS (80KB -> 2 blocks/CU) with register prefetch:
//   issue tile t+1 global loads before the (single) per-iteration barrier,
//   so they stay in flight across barrier + MFMA.
// ---------------------------------------------------------------------------
template<int EPI>
__global__ __launch_bounds__(512, 4)
void awq_gemm(const unsigned short* __restrict__ A,
              const int* __restrict__ qw, const int* __restrict__ qz,
              const float* __restrict__ sc,
              void* __restrict__ outp, const float* __restrict__ res,
              int N, int K)
{
    __shared__ unsigned short As[2][256 * 64];   // 2 x 32KB, swizzled 16B slots
    __shared__ unsigned short Bs[2][64 * 64];    // 2 x 8KB,  Bt[n][k] swizzled
    const int tid  = threadIdx.x;
    const int lane = tid & 63;
    const int wid  = tid >> 6;
    const int wm   = wid >> 1, wn = wid & 1;     // 4 x 2 waves
    const int m0   = blockIdx.y << 8;
    const int n0   = blockIdx.x << 6;
    const int NW   = N >> 3;

    // B dequant duty: one column, 8 k-rows
    const int bc  = tid & 63;
    const int bkg = tid >> 6;            // k-group 0..7
    const int gn  = n0 + bc;
    const int gwc = gn >> 3;
    const int nsh = (gn & 7) << 2;

    f32x4 acc[4][2];
#pragma unroll
    for (int i = 0; i < 4; i++)
#pragma unroll
        for (int j = 0; j < 2; j++) { f32x4 z = {0.f,0.f,0.f,0.f}; acc[i][j] = z; }

    // prefetch registers
    uint4v a_pf[4];
    unsigned int b_pf[8];
    float sc_pf;
    unsigned int zw_pf;

    auto issue = [&](int k0) {
#pragma unroll
        for (int i = 0; i < 4; i++) {
            int slot = tid + (i << 9);
            int row = slot >> 3, s = slot & 7;
            a_pf[i] = *(const uint4v*)(A + (size_t)(m0 + row) * K + k0 + ((s ^ (row & 7)) << 3));
        }
        const int* wp = qw + (size_t)(k0 + (bkg << 3)) * NW + gwc;
#pragma unroll
        for (int j = 0; j < 8; j++) b_pf[j] = (unsigned int)wp[(size_t)j * NW];
        int g = k0 >> 7;
        sc_pf = sc[(size_t)g * N + gn];
        zw_pf = (unsigned int)qz[(size_t)g * NW + gwc];
    };

    auto consume = [&](int buf) {
#pragma unroll
        for (int i = 0; i < 4; i++) {
            int slot = tid + (i << 9);
            *(uint4v*)(&As[buf][slot << 3]) = a_pf[i];
        }
        float scale = sc_pf;
        float nzs = -(float)((zw_pf >> nsh) & 0xFu) * scale;
        unsigned int pk[4];
#pragma unroll
        for (int j = 0; j < 4; j++) {
            float f0 = (float)((b_pf[2*j]   >> nsh) & 0xFu) * scale + nzs;
            float f1 = (float)((b_pf[2*j+1] >> nsh) & 0xFu) * scale + nzs;
            asm("v_cvt_pk_bf16_f32 %0, %1, %2" : "=v"(pk[j]) : "v"(f0), "v"(f1));
        }
        int s = bkg ^ (bc & 7);
        uint4v bv = {pk[0], pk[1], pk[2], pk[3]};
        *(uint4v*)(&Bs[buf][(bc << 6) + (s << 3)]) = bv;
    };

    const int NT = K >> 6;
    issue(0);
    int cur = 0;
    for (int t = 0; t < NT; t++) {
        consume(cur);                       // vmcnt waits inserted at reg use
        if (t + 1 < NT) issue((t + 1) << 6); // in flight across barrier + MFMA
        __syncthreads();
#pragma unroll
        for (int kk = 0; kk < 2; kk++) {
            const int srow = (kk << 2) + (lane >> 4);
            bf16x8 af[4], bfv[2];
#pragma unroll
            for (int mi = 0; mi < 4; mi++) {
                int r = (wm << 6) + (mi << 4) + (lane & 15);
                af[mi] = *(const bf16x8*)(&As[cur][(r << 6) + ((srow ^ (r & 7)) << 3)]);
            }
#pragma unroll
            for (int ni = 0; ni < 2; ni++) {
                int r = (wn << 5) + (ni << 4) + (lane & 15);
                bfv[ni] = *(const bf16x8*)(&Bs[cur][(r << 6) + ((srow ^ (r & 7)) << 3)]);
            }
#pragma unroll
            for (int mi = 0; mi < 4; mi++)
#pragma unroll
                for (int ni = 0; ni < 2; ni++)
                    acc[mi][ni] = __builtin_amdgcn_mfma_f32_16x16x32_bf16(af[mi], bfv[ni], acc[mi][ni], 0, 0, 0);
        }
        cur ^= 1;
    }

    // epilogue: C/D layout col=lane&15, row=(lane>>4)*4+reg
    const int rbase = m0 + (wm << 6) + ((lane >> 4) << 2);
    const int cbase = n0 + (wn << 5) + (lane & 15);
#pragma unroll
    for (int mi = 0; mi < 4; mi++) {
#pragma unroll
        for (int r = 0; r < 4; r++) {
            int row = rbase + (mi << 4) + r;
#pragma unroll
            for (int ni = 0; ni < 2; ni++) {
                int col = cbase + (ni << 4);
                float v = acc[mi][ni][r];
                if (EPI == 0) {
                    ((unsigned short*)outp)[(size_t)row * N + col] = f2bf(v);
                } else {
                    ((float*)outp)[(size_t)row * N + col] = v + res[(size_t)row * N + col];
                }
            }
        }
    }
}

// ---------------------------------------------------------------------------
// RoPE + layout glue: qkv bf16 [T,12288] ->
//   Qr [32][1024][128] (pre-scaled by 1/sqrt(128)), Kr [32][1024][128],
//   Vt [32][128][1024] (transposed V)
// ---------------------------------------------------------------------------
__global__ __launch_bounds__(256)
void rope_kernel(const int* __restrict__ positions, const unsigned short* __restrict__ qkv,
                 unsigned short* __restrict__ Qr, unsigned short* __restrict__ Kr,
                 unsigned short* __restrict__ Vtp)
{
    const int t = blockIdx.x, tid = threadIdx.x;
    const float p = (float)positions[t];
    const unsigned short* row = qkv + (size_t)t * 12288;
#pragma unroll 4
    for (int it = 0; it < 16; it++) {
        int task = (it << 8) + tid;           // 0..4095: [isK][head][i]
        int i   = task & 63;
        int hh  = (task >> 6) & 31;
        int isK = task >> 11;
        float fr = p * __expf(-(float)i * 0.14391156831f);
        float s, c;
        __sincosf(fr, &s, &c);
        const unsigned short* src = row + (isK << 12) + (hh << 7);
        float x1 = bf2f(src[i]);
        float x2 = bf2f(src[64 + i]);
        float o1 = x1 * c - x2 * s;
        float o2 = x2 * c + x1 * s;
        if (!isK) { o1 *= 0.08838834764831845f; o2 *= 0.08838834764831845f; }
        unsigned short* dst = (isK ? Kr : Qr) + ((size_t)hh * 1024 + t) * 128;
        dst[i]      = f2bf(o1);
        dst[64 + i] = f2bf(o2);
    }
#pragma unroll 4
    for (int it = 0; it < 16; it++) {
        int task = (it << 8) + tid;           // 0..4095: [head][d]
        int d = task & 127, hh = task >> 7;
        Vtp[((size_t)hh * 128 + d) * 1024 + t] = row[8192 + task];
    }
}

// ---------------------------------------------------------------------------
// Flash attention (causal). Block = (qt, head). 4 waves x 16 q-rows.
// ---------------------------------------------------------------------------
__global__ __launch_bounds__(256, 2)
void attn_kernel(const unsigned short* __restrict__ Qr, const unsigned short* __restrict__ Kr,
                 const unsigned short* __restrict__ Vtp, unsigned short* __restrict__ attn_out)
{
    __shared__ unsigned short Ks[64 * 128];    // [krow][d]
    __shared__ unsigned short Vs[128 * 64];    // [d][krow]
    __shared__ unsigned short Ps[4][16 * 64];  // per-wave P
    const int tid = threadIdx.x, lane = tid & 63, w = tid >> 6;
    const int qt = blockIdx.x, h = blockIdx.y;

    const unsigned short* Qh = Qr + ((size_t)h * 1024 + (size_t)qt * 64) * 128;

    bf16x8 qf[4];
#pragma unroll
    for (int kk = 0; kk < 4; kk++)
        qf[kk] = *(const bf16x8*)(Qh + (size_t)((w << 4) + (lane & 15)) * 128 + (kk << 5) + ((lane >> 4) << 3));

    f32x4 o[8];
#pragma unroll
    for (int i = 0; i < 8; i++) { f32x4 z = {0.f,0.f,0.f,0.f}; o[i] = z; }
    float Mr[4] = {-1e30f, -1e30f, -1e30f, -1e30f};
    float Lr[4] = {0.f, 0.f, 0.f, 0.f};
    const int qrow0 = (qt << 6) + (w << 4) + ((lane >> 4) << 2);

    for (int kt = 0; kt <= qt; kt++) {
        __syncthreads();
#pragma unroll
        for (int j = 0; j < 4; j++) {
            int slot = (j << 8) + tid;
            int rw = slot >> 4, s = slot & 15;
            int ssrc = (s & 8) | ((s ^ (rw & 7)) & 7);
            const uint4v* src = (const uint4v*)(Kr + ((size_t)h * 1024 + (size_t)kt * 64 + rw) * 128 + (ssrc << 3));
            *(uint4v*)(&Ks[(rw << 7) + (s << 3)]) = *src;
        }
#pragma unroll
        for (int j = 0; j < 4; j++) {
            int slot = (j << 8) + tid;
            int rw = slot >> 3, s = slot & 7;
            const uint4v* src = (const uint4v*)(Vtp + ((size_t)h * 128 + rw) * 1024 + (kt << 6) + ((s ^ (rw & 7)) << 3));
            *(uint4v*)(&Vs[(rw << 6) + (s << 3)]) = *src;
        }
        __syncthreads();

        f32x4 sc4[4];
#pragma unroll
        for (int ni = 0; ni < 4; ni++) { f32x4 z = {0.f,0.f,0.f,0.f}; sc4[ni] = z; }
#pragma unroll
        for (int kk = 0; kk < 4; kk++) {
#pragma unroll
            for (int ni = 0; ni < 4; ni++) {
                int r = (ni << 4) + (lane & 15);
                int s = (kk << 2) + (lane >> 4);
                int sp = (s & 8) | ((s ^ (r & 7)) & 7);
                bf16x8 kf = *(const bf16x8*)(&Ks[(r << 7) + (sp << 3)]);
                sc4[ni] = __builtin_amdgcn_mfma_f32_16x16x32_bf16(qf[kk], kf, sc4[ni], 0, 0, 0);
            }
        }

#pragma unroll
        for (int r = 0; r < 4; r++) {
            int qg = qrow0 + r;
            float mx = -1e30f;
#pragma unroll
            for (int ni = 0; ni < 4; ni++) {
                int kg_ = (kt << 6) + (ni << 4) + (lane & 15);
                float v = sc4[ni][r];
                if (kt == qt && kg_ > qg) { v = -1e30f; sc4[ni][r] = v; }
                mx = fmaxf(mx, v);
            }
#pragma unroll
            for (int m_ = 1; m_ < 16; m_ <<= 1) mx = fmaxf(mx, __shfl_xor(mx, m_));
            float mnew  = fmaxf(Mr[r], mx);
            float alpha = __expf(Mr[r] - mnew);
            Mr[r] = mnew;
            float rs = 0.f;
#pragma unroll
            for (int ni = 0; ni < 4; ni++) {
                float pv = __expf(sc4[ni][r] - mnew);
                sc4[ni][r] = pv;
                rs += pv;
            }
#pragma unroll
            for (int m_ = 1; m_ < 16; m_ <<= 1) rs += __shfl_xor(rs, m_);
            Lr[r] = Lr[r] * alpha + rs;
#pragma unroll
            for (int nd = 0; nd < 8; nd++) o[nd][r] *= alpha;
        }

#pragma unroll
        for (int r = 0; r < 4; r++) {
            int qr = ((lane >> 4) << 2) + r;
#pragma unroll
            for (int ni = 0; ni < 4; ni++) {
                int col = (ni << 4) + (lane & 15);
                int phys = (col >> 3) ^ (qr & 7);
                Ps[w][(qr << 6) + (phys << 3) + (col & 7)] = f2bf(sc4[ni][r]);
            }
        }
#pragma unroll
        for (int kk2 = 0; kk2 < 2; kk2++) {
            int rowp = lane & 15;
            int sl = (kk2 << 2) + (lane >> 4);
            bf16x8 pa = *(const bf16x8*)(&Ps[w][(rowp << 6) + ((sl ^ (rowp & 7)) << 3)]);
#pragma unroll
            for (int nd = 0; nd < 8; nd++) {
                int rv = (nd << 4) + (lane & 15);
                bf16x8 vb = *(const bf16x8*)(&Vs[(rv << 6) + ((sl ^ (rv & 7)) << 3)]);
                o[nd] = __builtin_amdgcn_mfma_f32_16x16x32_bf16(pa, vb, o[nd], 0, 0, 0);
            }
        }
    }

#pragma unroll
    for (int r = 0; r < 4; r++) {
        float inv = 1.0f / Lr[r];
        int trow = qrow0 + r;
#pragma unroll
        for (int nd = 0; nd < 8; nd++) {
            int col = (h << 7) + (nd << 4) + (lane & 15);
            attn_out[(size_t)trow * 4096 + col] = f2bf(o[nd][r] * inv);
        }
    }
}

// ---------------------------------------------------------------------------
// silu(gate) * up, bf16, in-place into `up` (recomputed each call)
// ---------------------------------------------------------------------------
__global__ __launch_bounds__(256)
void silu_mul_kernel(const unsigned short* __restrict__ gate, unsigned short* __restrict__ up)
{
    size_t idx = ((size_t)blockIdx.x * 256 + threadIdx.x) * 8;
    uint4v g = *(const uint4v*)(gate + idx);
    uint4v u = *(const uint4v*)(up + idx);
    unsigned int outp[4];
#pragma unroll
    for (int j = 0; j < 4; j++) {
        unsigned int gw = g[j], uw = u[j];
        float g0 = bf2f((unsigned short)(gw & 0xFFFF)), g1 = bf2f((unsigned short)(gw >> 16));
        float u0 = bf2f((unsigned short)(uw & 0xFFFF)), u1 = bf2f((unsigned short)(uw >> 16));
        float s0 = g0 / (1.f + __expf(-g0)) * u0;
        float s1 = g1 / (1.f + __expf(-g1)) * u1;
        outp[j] = (unsigned int)f2bf(s0) | ((unsigned int)f2bf(s1) << 16);
    }
    uint4v ov = {outp[0], outp[1], outp[2], outp[3]};
    *(uint4v*)(up + idx) = ov;
}

// ---------------------------------------------------------------------------
// Launcher
// ---------------------------------------------------------------------------
extern "C" void kernel_launch(void* const* d_in, const int* in_sizes, int n_in,
                              void* d_out, int out_size, void* d_ws, size_t ws_size,
                              hipStream_t stream)
{
    const int*   positions = (const int*)  d_in[0];
    const float* hidden    = (const float*)d_in[1];
    const float* ln1       = (const float*)d_in[2];
    const float* ln2       = (const float*)d_in[3];
    const int*   qkv_qw    = (const int*)  d_in[4];
    const int*   qkv_qz    = (const int*)  d_in[5];
    const float* qkv_sc    = (const float*)d_in[6];
    const int*   o_qw      = (const int*)  d_in[7];
    const int*   o_qz      = (const int*)  d_in[8];
    const float* o_sc      = (const float*)d_in[9];
    const int*   gate_qw   = (const int*)  d_in[10];
    const int*   gate_qz   = (const int*)  d_in[11];
    const float* gate_sc   = (const float*)d_in[12];
    const int*   up_qw     = (const int*)  d_in[13];
    const int*   up_qz     = (const int*)  d_in[14];
    const float* up_sc     = (const float*)d_in[15];
    const int*   down_qw   = (const int*)  d_in[16];
    const int*   down_qz   = (const int*)  d_in[17];
    const float* down_sc   = (const float*)d_in[18];

    char* ws = (char*)d_ws;
    unsigned short* xln   = (unsigned short*)(ws + 0);          //  8.39 MB [T,H] bf16
    unsigned short* qkvb  = (unsigned short*)(ws + 8388608);    // 25.17 MB [T,3H] bf16
    unsigned short* Qrp   = (unsigned short*)(ws + 33554432);   //  8.39 MB
    unsigned short* Krp   = (unsigned short*)(ws + 41943040);   //  8.39 MB
    unsigned short* Vtp   = (unsigned short*)(ws + 50331648);   //  8.39 MB
    unsigned short* attnb = (unsigned short*)(ws + 58720256);   //  8.39 MB [T,H] bf16
    float*          hid   = (float*)        (ws + 67108864);    // 16.78 MB [T,H] f32
    unsigned short* x2    = (unsigned short*)(ws + 0);          // reuse xln
    unsigned short* gateb = (unsigned short*)(ws + 8388608);    // reuse qkvb
    unsigned short* upb   = (unsigned short*)(ws + 33554432);   // reuse Q/K

    // --- attention block ---
    rmsnorm_kernel<<<1024, 256, 0, stream>>>(hidden, ln1, xln);
    awq_gemm<0><<<dim3(192, 4), 512, 0, stream>>>(xln, qkv_qw, qkv_qz, qkv_sc,
                                                  (void*)qkvb, nullptr, 12288, 4096);
    rope_kernel<<<1024, 256, 0, stream>>>(positions, qkvb, Qrp, Krp, Vtp);
    attn_kernel<<<dim3(16, 32), 256, 0, stream>>>(Qrp, Krp, Vtp, attnb);
    awq_gemm<1><<<dim3(64, 4), 512, 0, stream>>>(attnb, o_qw, o_qz, o_sc,
                                                 (void*)hid, hidden, 4096, 4096);
    // --- MLP block ---
    rmsnorm_kernel<<<1024, 256, 0, stream>>>(hid, ln2, x2);
    awq_gemm<0><<<dim3(172, 4), 512, 0, stream>>>(x2, gate_qw, gate_qz, gate_sc,
                                                  (void*)gateb, nullptr, 11008, 4096);
    awq_gemm<0><<<dim3(172, 4), 512, 0, stream>>>(x2, up_qw, up_qz, up_sc,
                                                  (void*)upb, nullptr, 11008, 4096);
    silu_mul_kernel<<<5504, 256, 0, stream>>>(gateb, upb);
    awq_gemm<1><<<dim3(64, 4), 512, 0, stream>>>(upb, down_qw, down_qz, down_sc,
                                                 d_out, hid, 4096, 11008);
}